// Round 11
// baseline (120.701 us; speedup 1.0000x reference)
//
#include <hip/hip_runtime.h>

typedef _Float16 f16x8 __attribute__((ext_vector_type(8)));
typedef float f32x4 __attribute__((ext_vector_type(4)));

// ---------------- gate primitives (state: 128 amps, 2 per lane) -------------
// amp index i = (r<<6) | lane, wire w <-> bit (6-w) (wire 0 = MSB)

__device__ __forceinline__ void ry_gate(float& a0, float& a1, int w, int lane,
                                        float c, float s) {
  if (w == 0) {
    float n0 = c * a0 - s * a1;
    float n1 = s * a0 + c * a1;
    a0 = n0; a1 = n1;
  } else {
    int m = 1 << (6 - w);
    float p0 = __shfl_xor(a0, m);
    float p1 = __shfl_xor(a1, m);
    if (lane & m) {
      a0 = s * p0 + c * a0;
      a1 = s * p1 + c * a1;
    } else {
      a0 = c * a0 - s * p0;
      a1 = c * a1 - s * p1;
    }
  }
}

__device__ __forceinline__ void cnot_gate(float& a0, float& a1, int c, int t,
                                          int lane) {
  if (c == 0) {            // control = wire0 (bit6): r==1 half gets target flip
    int mt = 1 << (6 - t);
    a1 = __shfl_xor(a1, mt);
  } else if (t == 0) {     // target = wire0: swap a0<->a1 where control bit set
    int mc = 1 << (6 - c);
    if (lane & mc) { float tmp = a0; a0 = a1; a1 = tmp; }
  } else {
    int mc = 1 << (6 - c), mt = 1 << (6 - t);
    float p0 = __shfl_xor(a0, mt);
    float p1 = __shfl_xor(a1, mt);
    if (lane & mc) { a0 = p0; a1 = p1; }
  }
}

// --------- single fused kernel: basis (blocks 0..127) + flag + gemm ---------
// Full grid co-resident by construction: 1024 blocks x 32 KB LDS -> 5/CU cap
// (1280 slots >= 1024), VGPR ~60, 4x256 thr/CU. Producers always run.
// Consumers spin on a device-scope atomic LOAD (not RMW — round-10 lesson:
// RMW spin serializes at the LLC slice, ~134 us; loads are served ~few cy).
// W layout in d_ws: MFMA B-FRAGMENT order,
//   element (n,k): f16 idx = ((k>>5)*8+(n>>4))*512 + ((k>>3)&3)*128 + (n&15)*8 + (k&7)
__global__ __launch_bounds__(256, 4) void fused_qcnn(
    const float* __restrict__ X,
    const float* __restrict__ qc1, const float* __restrict__ qc2,
    const float* __restrict__ qc3, const float* __restrict__ qc4,
    const float* __restrict__ qc5, const float* __restrict__ qc6,
    const float* __restrict__ qp1, const float* __restrict__ qp2,
    const float* __restrict__ qp3, const float* __restrict__ qp4,
    const float* __restrict__ qp5, const float* __restrict__ qp6,
    const float* __restrict__ qf,
    _Float16* __restrict__ wt, unsigned* __restrict__ flag,
    float* __restrict__ out, int M) {
  __shared__ uint4 ldsbuf[2048];  // phase 0: cs table (1.7 KB); phase 1: W (32 KB)
  int tid = threadIdx.x;
  int wave = tid >> 6, lane = tid & 63;
  int lr = lane & 15;
  int g = lane >> 4;
  int lk = g * 8;

  size_t base0 = (size_t)blockIdx.x * 256 + wave * 16;  // this wave's row base

  // issue tile-0 X prefetch FIRST — the L3 stream starts while basis runs
  float4 v0[4], v1[4];
  if (base0 < (size_t)M) {
    const float* xp = X + (base0 + lr) * 128 + lk;
#pragma unroll
    for (int ks = 0; ks < 4; ++ks) {
      v0[ks] = *(const float4*)(xp + ks * 32);
      v1[ks] = *(const float4*)(xp + ks * 32 + 4);
    }
  }

  // ---------------- phase 0: basis (blocks 0..127 only) ----------------
  if (blockIdx.x < 128) {
    float2* cs = (float2*)ldsbuf;
    {
      const float* arrs[13] = {qc1, qp1, qc2, qp2, qc3, qp3, qc4,
                               qp4, qc5, qp5, qc6, qp6, qf};
      const int sizes[13] = {42, 12, 36, 10, 30, 8, 24, 6, 18, 4, 12, 2, 1};
      for (int t = tid; t < 205; t += 256) {
        int base = 0; float ang = 0.f;
#pragma unroll
        for (int s2 = 0; s2 < 13; ++s2) {
          if (t >= base && t < base + sizes[s2]) ang = arrs[s2][t - base];
          base += sizes[s2];
        }
        float h = 0.5f * ang;
        cs[t] = make_float2(cosf(h), sinf(h));
      }
    }
    __syncthreads();

    if (wave == 0) {
      int k = blockIdx.x;  // basis column
      float a0 = ((k >> 6) == 0 && (k & 63) == lane) ? 1.0f : 0.0f;
      float a1 = ((k >> 6) == 1 && (k & 63) == lane) ? 1.0f : 0.0f;
      int gi = 0;

      const int qcstep[6] = {4, 1, 2, 1, 1, 1};
#define RYG(w)                                        \
  { float2 csv = cs[gi++]; ry_gate(a0, a1, (w), lane, csv.x, csv.y); }
#define CNG(c, t) cnot_gate(a0, a1, (c), (t), lane);

#pragma unroll
      for (int j = 0; j < 6; ++j) {
        int sq = 7 - j;
        int step = qcstep[j];
        for (int i = 0; i < sq; ++i) { RYG(i); }
        for (int i = 0; i < sq; ++i) {
          if (i == 0) { RYG(0); CNG(sq - 1, 0); RYG(0); }
          else { int w = sq - i; RYG(w); CNG(w - 1, w); RYG(w); }
        }
        for (int i = 0; i < sq; ++i) { RYG(i); }
        int control = 0, controled = step;
        for (int i = 0; i < sq; ++i) {
          RYG(controled); CNG(control, controled); RYG(controled);
          control = controled; controled = (controled + step) % sq;
        }
        for (int i = 0; i < sq - 1; ++i) { RYG(i + 1); CNG(i, i + 1); RYG(i + 1); }
      }
      RYG(0);  // final QF rotation (index 204)
#undef RYG
#undef CNG

      // scatter to fragment order
      int ks = k >> 5, khi = (k >> 3) & 3, j = k & 7;
      int nf0 = lane >> 4, lr0 = lane & 15;
      wt[(ks * 8 + nf0) * 512 + khi * 128 + lr0 * 8 + j] = (_Float16)a0;
      wt[(ks * 8 + nf0 + 4) * 512 + khi * 128 + lr0 * 8 + j] = (_Float16)a1;
      __threadfence();  // device-scope release: W visible before the signal
      if (lane == 0)
        __hip_atomic_fetch_add(flag, 1u, __ATOMIC_RELEASE,
                               __HIP_MEMORY_SCOPE_AGENT);
    }
    __syncthreads();  // wave 0 done with cs before LDS is overwritten with W
  }

  // ---------------- wait for all 128 basis columns ----------------
  // Atomic LOAD spin (agent scope) with ~0.85 us backoff: no RMW serialization.
  if (tid == 0) {
    while (__hip_atomic_load(flag, __ATOMIC_RELAXED,
                             __HIP_MEMORY_SCOPE_AGENT) < 128u)
      __builtin_amdgcn_s_sleep(32);
  }
  __syncthreads();
  __threadfence();  // acquire: drop stale wt lines before the LDS stage

  // ---------------- phase 1: gemm (identical to round 6) ----------------
  // stage W -> LDS: straight linear copy, fully coalesced
  {
    const uint4* wv = (const uint4*)wt;
#pragma unroll
    for (int c = 0; c < 8; ++c) ldsbuf[c * 256 + tid] = wv[c * 256 + tid];
  }
  __syncthreads();

  const char* bbase = (const char*)ldsbuf + lane * 16;

#pragma unroll
  for (int t = 0; t < 4; ++t) {
    size_t rb = base0 + (size_t)t * 64;
    if (rb < (size_t)M) {
      // convert current tile to f16 A-fragments (frees v0/v1)
      f16x8 a[4];
#pragma unroll
      for (int ks = 0; ks < 4; ++ks) {
        auto p0 = __builtin_amdgcn_cvt_pkrtz(v0[ks].x, v0[ks].y);
        auto p1 = __builtin_amdgcn_cvt_pkrtz(v0[ks].z, v0[ks].w);
        auto p2 = __builtin_amdgcn_cvt_pkrtz(v1[ks].x, v1[ks].y);
        auto p3 = __builtin_amdgcn_cvt_pkrtz(v1[ks].z, v1[ks].w);
        f16x8 f;
        f[0] = (_Float16)p0[0]; f[1] = (_Float16)p0[1];
        f[2] = (_Float16)p1[0]; f[3] = (_Float16)p1[1];
        f[4] = (_Float16)p2[0]; f[5] = (_Float16)p2[1];
        f[6] = (_Float16)p3[0]; f[7] = (_Float16)p3[1];
        a[ks] = f;
      }

      // issue next tile's loads early — in flight during MFMA + epilogue
      if (t < 3) {
        size_t rn = base0 + (size_t)(t + 1) * 64;
        if (rn < (size_t)M) {
          const float* xp = X + (rn + lr) * 128 + lk;
#pragma unroll
          for (int ks = 0; ks < 4; ++ks) {
            v0[ks] = *(const float4*)(xp + ks * 32);
            v1[ks] = *(const float4*)(xp + ks * 32 + 4);
          }
        }
      }

      f32x4 acc[8];
#pragma unroll
      for (int nf = 0; nf < 8; ++nf) acc[nf] = (f32x4){0.f, 0.f, 0.f, 0.f};

#pragma unroll
      for (int ks = 0; ks < 4; ++ks) {
#pragma unroll
        for (int nf = 0; nf < 8; ++nf) {
          f16x8 b = *(const f16x8*)(bbase + (ks * 8 + nf) * 1024);
          acc[nf] = __builtin_amdgcn_mfma_f32_16x16x32_f16(a[ks], b, acc[nf], 0, 0, 0);
        }
      }

      // epilogue: s0 = sum_{n<64} z^2, s1 = sum_{n>=64} z^2 per row
      float s0[4], s1[4];
#pragma unroll
      for (int r = 0; r < 4; ++r) {
        float t0 = 0.f, t1 = 0.f;
#pragma unroll
        for (int nf = 0; nf < 4; ++nf) t0 += acc[nf][r] * acc[nf][r];
#pragma unroll
        for (int nf = 4; nf < 8; ++nf) t1 += acc[nf][r] * acc[nf][r];
        s0[r] = t0; s1[r] = t1;
      }
#pragma unroll
      for (int d = 1; d < 16; d <<= 1) {  // reduce across the 16-lane group
#pragma unroll
        for (int r = 0; r < 4; ++r) {
          s0[r] += __shfl_xor(s0[r], d);
          s1[r] += __shfl_xor(s1[r], d);
        }
      }
      size_t row = rb + g * 4;
#pragma unroll
      for (int r = 0; r < 4; ++r) {
        if ((lane & 15) == r) {
          float inv = 1.0f / (s0[r] + s1[r]);
          *(float2*)(out + (row + r) * 2) =
              make_float2(s0[r] * inv, s1[r] * inv);
        }
      }
    }
  }
}

// ---------------------------------------------------------------------------
extern "C" void kernel_launch(void* const* d_in, const int* in_sizes, int n_in,
                              void* d_out, int out_size, void* d_ws,
                              size_t ws_size, hipStream_t stream) {
  // setup_inputs() dict order is INTERLEAVED: x, QC1, QP1, QC2, QP2, ...,
  // QC6, QP6, QF.
  const float* X = (const float*)d_in[0];
  _Float16* wt = (_Float16*)d_ws;                       // 32 KB, fragment order
  unsigned* flag = (unsigned*)((char*)d_ws + 32768);    // producer counter

  // zero the flag every call (graph-capturable async memset; determinism)
  hipMemsetAsync(flag, 0, sizeof(unsigned), stream);

  int M = in_sizes[0] / 128;   // 262144
  int nblk = (M + 255) / 256;  // 1024 blocks — fully co-resident (5/CU cap)

  fused_qcnn<<<nblk, 256, 0, stream>>>(
      X,
      /*qc1*/ (const float*)d_in[1], /*qc2*/ (const float*)d_in[3],
      /*qc3*/ (const float*)d_in[5], /*qc4*/ (const float*)d_in[7],
      /*qc5*/ (const float*)d_in[9], /*qc6*/ (const float*)d_in[11],
      /*qp1*/ (const float*)d_in[2], /*qp2*/ (const float*)d_in[4],
      /*qp3*/ (const float*)d_in[6], /*qp4*/ (const float*)d_in[8],
      /*qp5*/ (const float*)d_in[10], /*qp6*/ (const float*)d_in[12],
      /*qf*/ (const float*)d_in[13], wt, flag, (float*)d_out, M);
}

// Round 12
// 56.257 us; speedup vs baseline: 2.1455x; 2.1455x over previous
//
#include <hip/hip_runtime.h>

typedef _Float16 f16x8 __attribute__((ext_vector_type(8)));
typedef float f32x4 __attribute__((ext_vector_type(4)));

#define NC 4  // columns per wave in basis: 4 independent gate-chains interleave
              // in one wave -> per-gate shfl latency amortized 4x (ILP)

// ---------------- gate primitives (state: 128 amps, 2 per lane) -------------
// amp index i = (r<<6) | lane, wire w <-> bit (6-w) (wire 0 = MSB)
// Vectorized over NC independent columns.

__device__ __forceinline__ void ry_gate(float a0[NC], float a1[NC], int w,
                                        int lane, float c, float s) {
  if (w == 0) {
#pragma unroll
    for (int q = 0; q < NC; ++q) {
      float n0 = c * a0[q] - s * a1[q];
      float n1 = s * a0[q] + c * a1[q];
      a0[q] = n0; a1[q] = n1;
    }
  } else {
    int m = 1 << (6 - w);
#pragma unroll
    for (int q = 0; q < NC; ++q) {
      float p0 = __shfl_xor(a0[q], m);
      float p1 = __shfl_xor(a1[q], m);
      if (lane & m) {
        a0[q] = s * p0 + c * a0[q];
        a1[q] = s * p1 + c * a1[q];
      } else {
        a0[q] = c * a0[q] - s * p0;
        a1[q] = c * a1[q] - s * p1;
      }
    }
  }
}

__device__ __forceinline__ void cnot_gate(float a0[NC], float a1[NC], int c,
                                          int t, int lane) {
  if (c == 0) {            // control = wire0 (bit6): r==1 half gets target flip
    int mt = 1 << (6 - t);
#pragma unroll
    for (int q = 0; q < NC; ++q) a1[q] = __shfl_xor(a1[q], mt);
  } else if (t == 0) {     // target = wire0: swap a0<->a1 where control bit set
    int mc = 1 << (6 - c);
    if (lane & mc) {
#pragma unroll
      for (int q = 0; q < NC; ++q) {
        float tmp = a0[q]; a0[q] = a1[q]; a1[q] = tmp;
      }
    }
  } else {
    int mc = 1 << (6 - c), mt = 1 << (6 - t);
#pragma unroll
    for (int q = 0; q < NC; ++q) {
      float p0 = __shfl_xor(a0[q], mt);
      float p1 = __shfl_xor(a1[q], mt);
      if (lane & mc) { a0[q] = p0; a1[q] = p1; }
    }
  }
}

// ------- kernel 1: build U, store in MFMA B-FRAGMENT order (f16) -----------
// Each wave evolves NC basis columns simultaneously (independent chains, ILP).
// frag layout: element (n,k):
//   f16 idx = ((k>>5)*8 + (n>>4))*512 + ((k>>3)&3)*128 + (n&15)*8 + (k&7)
__global__ __launch_bounds__(64) void basis_kernel(
    const float* __restrict__ qc1, const float* __restrict__ qc2,
    const float* __restrict__ qc3, const float* __restrict__ qc4,
    const float* __restrict__ qc5, const float* __restrict__ qc6,
    const float* __restrict__ qp1, const float* __restrict__ qp2,
    const float* __restrict__ qp3, const float* __restrict__ qp4,
    const float* __restrict__ qp5, const float* __restrict__ qp6,
    const float* __restrict__ qf, _Float16* __restrict__ wt) {
  __shared__ float2 cs[208];
  int lane = threadIdx.x;

  // angles laid out flat: [QC1,QP1,QC2,QP2,...,QC6,QP6,QF] -> (cos,sin)(a/2)
  {
    const float* arrs[13] = {qc1, qp1, qc2, qp2, qc3, qp3, qc4,
                             qp4, qc5, qp5, qc6, qp6, qf};
    const int sizes[13] = {42, 12, 36, 10, 30, 8, 24, 6, 18, 4, 12, 2, 1};
    for (int t = lane; t < 205; t += 64) {
      int base = 0; float ang = 0.f;
#pragma unroll
      for (int s2 = 0; s2 < 13; ++s2) {
        if (t >= base && t < base + sizes[s2]) ang = arrs[s2][t - base];
        base += sizes[s2];
      }
      float h = 0.5f * ang;
      cs[t] = make_float2(cosf(h), sinf(h));
    }
  }
  __syncthreads();

  int k0 = blockIdx.x * NC;  // first basis column of this wave
  float a0[NC], a1[NC];
#pragma unroll
  for (int q = 0; q < NC; ++q) {
    int k = k0 + q;
    a0[q] = ((k >> 6) == 0 && (k & 63) == lane) ? 1.0f : 0.0f;
    a1[q] = ((k >> 6) == 1 && (k & 63) == lane) ? 1.0f : 0.0f;
  }
  int gi = 0;

  const int qcstep[6] = {4, 1, 2, 1, 1, 1};
#define RYG(w)                                        \
  { float2 csv = cs[gi++]; ry_gate(a0, a1, (w), lane, csv.x, csv.y); }
#define CNG(c, t) cnot_gate(a0, a1, (c), (t), lane);

#pragma unroll
  for (int j = 0; j < 6; ++j) {
    int sq = 7 - j;
    int step = qcstep[j];
    for (int i = 0; i < sq; ++i) { RYG(i); }
    for (int i = 0; i < sq; ++i) {
      if (i == 0) { RYG(0); CNG(sq - 1, 0); RYG(0); }
      else { int w = sq - i; RYG(w); CNG(w - 1, w); RYG(w); }
    }
    for (int i = 0; i < sq; ++i) { RYG(i); }
    int control = 0, controled = step;
    for (int i = 0; i < sq; ++i) {
      RYG(controled); CNG(control, controled); RYG(controled);
      control = controled; controled = (controled + step) % sq;
    }
    for (int i = 0; i < sq - 1; ++i) { RYG(i + 1); CNG(i, i + 1); RYG(i + 1); }
  }
  RYG(0);  // final QF rotation (index 204)
#undef RYG
#undef CNG

  // scatter to fragment order
#pragma unroll
  for (int q = 0; q < NC; ++q) {
    int k = k0 + q;
    int ks = k >> 5, khi = (k >> 3) & 3, j = k & 7;
    int nf0 = lane >> 4, lr0 = lane & 15;
    wt[(ks * 8 + nf0) * 512 + khi * 128 + lr0 * 8 + j] = (_Float16)a0[q];
    wt[(ks * 8 + nf0 + 4) * 512 + khi * 128 + lr0 * 8 + j] = (_Float16)a1[q];
  }
}

// ---------------- kernel 2: Z = X * U^T, out = row-half prob ----------------
// (byte-identical to round 6 — proven 42.3 us total, no LDS conflicts,
//  VGPR 64, fragment-order W in LDS, 4 tiles of 64 rows per block)
__global__ __launch_bounds__(256, 4) void qcnn_gemm(
    const float* __restrict__ X, const _Float16* __restrict__ wt,
    float* __restrict__ out, int M) {
  __shared__ uint4 ldsbuf[2048];  // 32 KB: W in fragment order
  int tid = threadIdx.x;
  int wave = tid >> 6, lane = tid & 63;
  int lr = lane & 15;
  int g = lane >> 4;
  int lk = g * 8;

  size_t base0 = (size_t)blockIdx.x * 256 + wave * 16;  // this wave's row base

  // prefetch iter-0 X loads (in flight during LDS staging + barrier)
  float4 v0[4], v1[4];
  if (base0 < (size_t)M) {
    const float* xp = X + (base0 + lr) * 128 + lk;
#pragma unroll
    for (int ks = 0; ks < 4; ++ks) {
      v0[ks] = *(const float4*)(xp + ks * 32);
      v1[ks] = *(const float4*)(xp + ks * 32 + 4);
    }
  }

  // stage W -> LDS: straight linear copy, fully coalesced
  {
    const uint4* wv = (const uint4*)wt;
#pragma unroll
    for (int c = 0; c < 8; ++c) ldsbuf[c * 256 + tid] = wv[c * 256 + tid];
  }
  __syncthreads();

  const char* bbase = (const char*)ldsbuf + lane * 16;

#pragma unroll
  for (int t = 0; t < 4; ++t) {
    size_t rb = base0 + (size_t)t * 64;
    if (rb < (size_t)M) {
      // convert current tile to f16 A-fragments (frees v0/v1)
      f16x8 a[4];
#pragma unroll
      for (int ks = 0; ks < 4; ++ks) {
        auto p0 = __builtin_amdgcn_cvt_pkrtz(v0[ks].x, v0[ks].y);
        auto p1 = __builtin_amdgcn_cvt_pkrtz(v0[ks].z, v0[ks].w);
        auto p2 = __builtin_amdgcn_cvt_pkrtz(v1[ks].x, v1[ks].y);
        auto p3 = __builtin_amdgcn_cvt_pkrtz(v1[ks].z, v1[ks].w);
        f16x8 f;
        f[0] = (_Float16)p0[0]; f[1] = (_Float16)p0[1];
        f[2] = (_Float16)p1[0]; f[3] = (_Float16)p1[1];
        f[4] = (_Float16)p2[0]; f[5] = (_Float16)p2[1];
        f[6] = (_Float16)p3[0]; f[7] = (_Float16)p3[1];
        a[ks] = f;
      }

      // issue next tile's loads early — in flight during MFMA + epilogue
      if (t < 3) {
        size_t rn = base0 + (size_t)(t + 1) * 64;
        if (rn < (size_t)M) {
          const float* xp = X + (rn + lr) * 128 + lk;
#pragma unroll
          for (int ks = 0; ks < 4; ++ks) {
            v0[ks] = *(const float4*)(xp + ks * 32);
            v1[ks] = *(const float4*)(xp + ks * 32 + 4);
          }
        }
      }

      f32x4 acc[8];
#pragma unroll
      for (int nf = 0; nf < 8; ++nf) acc[nf] = (f32x4){0.f, 0.f, 0.f, 0.f};

#pragma unroll
      for (int ks = 0; ks < 4; ++ks) {
#pragma unroll
        for (int nf = 0; nf < 8; ++nf) {
          f16x8 b = *(const f16x8*)(bbase + (ks * 8 + nf) * 1024);
          acc[nf] = __builtin_amdgcn_mfma_f32_16x16x32_f16(a[ks], b, acc[nf], 0, 0, 0);
        }
      }

      // epilogue: s0 = sum_{n<64} z^2, s1 = sum_{n>=64} z^2 per row
      float s0[4], s1[4];
#pragma unroll
      for (int r = 0; r < 4; ++r) {
        float t0 = 0.f, t1 = 0.f;
#pragma unroll
        for (int nf = 0; nf < 4; ++nf) t0 += acc[nf][r] * acc[nf][r];
#pragma unroll
        for (int nf = 4; nf < 8; ++nf) t1 += acc[nf][r] * acc[nf][r];
        s0[r] = t0; s1[r] = t1;
      }
#pragma unroll
      for (int d = 1; d < 16; d <<= 1) {  // reduce across the 16-lane group
#pragma unroll
        for (int r = 0; r < 4; ++r) {
          s0[r] += __shfl_xor(s0[r], d);
          s1[r] += __shfl_xor(s1[r], d);
        }
      }
      size_t row = rb + g * 4;
#pragma unroll
      for (int r = 0; r < 4; ++r) {
        if ((lane & 15) == r) {
          float inv = 1.0f / (s0[r] + s1[r]);
          *(float2*)(out + (row + r) * 2) =
              make_float2(s0[r] * inv, s1[r] * inv);
        }
      }
    }
  }
}

// ---------------------------------------------------------------------------
extern "C" void kernel_launch(void* const* d_in, const int* in_sizes, int n_in,
                              void* d_out, int out_size, void* d_ws,
                              size_t ws_size, hipStream_t stream) {
  const float* X = (const float*)d_in[0];
  _Float16* wt = (_Float16*)d_ws;  // 128*128 f16 = 32 KB, fragment order

  // setup_inputs() dict order is INTERLEAVED: x, QC1, QP1, QC2, QP2, ...,
  // QC6, QP6, QF.
  basis_kernel<<<128 / NC, 64, 0, stream>>>(
      /*qc1*/ (const float*)d_in[1], /*qc2*/ (const float*)d_in[3],
      /*qc3*/ (const float*)d_in[5], /*qc4*/ (const float*)d_in[7],
      /*qc5*/ (const float*)d_in[9], /*qc6*/ (const float*)d_in[11],
      /*qp1*/ (const float*)d_in[2], /*qp2*/ (const float*)d_in[4],
      /*qp3*/ (const float*)d_in[6], /*qp4*/ (const float*)d_in[8],
      /*qp5*/ (const float*)d_in[10], /*qp6*/ (const float*)d_in[12],
      /*qf*/ (const float*)d_in[13], wt);

  int M = in_sizes[0] / 128;   // 262144
  int nblk = (M + 255) / 256;  // 1024 blocks of 256 rows
  qcnn_gemm<<<nblk, 256, 0, stream>>>(X, wt, (float*)d_out, M);
}

// Round 13
// 44.464 us; speedup vs baseline: 2.7146x; 1.2652x over previous
//
#include <hip/hip_runtime.h>

typedef _Float16 f16x8 __attribute__((ext_vector_type(8)));
typedef float f32x16 __attribute__((ext_vector_type(16)));

// ---------------- gate primitives (state: 128 amps, 2 per lane) -------------
// amp index i = (r<<6) | lane, wire w <-> bit (6-w) (wire 0 = MSB)

__device__ __forceinline__ void ry_gate(float& a0, float& a1, int w, int lane,
                                        float c, float s) {
  if (w == 0) {
    float n0 = c * a0 - s * a1;
    float n1 = s * a0 + c * a1;
    a0 = n0; a1 = n1;
  } else {
    int m = 1 << (6 - w);
    float p0 = __shfl_xor(a0, m);
    float p1 = __shfl_xor(a1, m);
    if (lane & m) {
      a0 = s * p0 + c * a0;
      a1 = s * p1 + c * a1;
    } else {
      a0 = c * a0 - s * p0;
      a1 = c * a1 - s * p1;
    }
  }
}

__device__ __forceinline__ void cnot_gate(float& a0, float& a1, int c, int t,
                                          int lane) {
  if (c == 0) {            // control = wire0 (bit6): r==1 half gets target flip
    int mt = 1 << (6 - t);
    a1 = __shfl_xor(a1, mt);
  } else if (t == 0) {     // target = wire0: swap a0<->a1 where control bit set
    int mc = 1 << (6 - c);
    if (lane & mc) { float tmp = a0; a0 = a1; a1 = tmp; }
  } else {
    int mc = 1 << (6 - c), mt = 1 << (6 - t);
    float p0 = __shfl_xor(a0, mt);
    float p1 = __shfl_xor(a1, mt);
    if (lane & mc) { a0 = p0; a1 = p1; }
  }
}

// ------- kernel 1: build U, store in 32x32x16 B-FRAGMENT order (f16) -------
// B frag (ks,nf): 1024 B at (ks*4+nf)*1024; lane l holds 16 B at +l*16 =
//   B[k = ks*16 + (l>>5)*8 + j][col = nf*32 + (l&31)] = U[n=col][k], j=0..7.
// => element (n,k): f16 idx = ((k>>4)*4 + (n>>5))*512 + ((k>>3)&1)*256 + (n&31)*8 + (k&7)
// (single column per 64-thread block — round-12 lesson: shfl chains are
//  DS-issue-bound per wave; ILP over columns made it 4x slower)
__global__ __launch_bounds__(64) void basis_kernel(
    const float* __restrict__ qc1, const float* __restrict__ qc2,
    const float* __restrict__ qc3, const float* __restrict__ qc4,
    const float* __restrict__ qc5, const float* __restrict__ qc6,
    const float* __restrict__ qp1, const float* __restrict__ qp2,
    const float* __restrict__ qp3, const float* __restrict__ qp4,
    const float* __restrict__ qp5, const float* __restrict__ qp6,
    const float* __restrict__ qf, _Float16* __restrict__ wt) {
  __shared__ float2 cs[208];
  int lane = threadIdx.x;

  // angles laid out flat: [QC1,QP1,QC2,QP2,...,QC6,QP6,QF] -> (cos,sin)(a/2)
  {
    const float* arrs[13] = {qc1, qp1, qc2, qp2, qc3, qp3, qc4,
                             qp4, qc5, qp5, qc6, qp6, qf};
    const int sizes[13] = {42, 12, 36, 10, 30, 8, 24, 6, 18, 4, 12, 2, 1};
    for (int t = lane; t < 205; t += 64) {
      int base = 0; float ang = 0.f;
#pragma unroll
      for (int s2 = 0; s2 < 13; ++s2) {
        if (t >= base && t < base + sizes[s2]) ang = arrs[s2][t - base];
        base += sizes[s2];
      }
      float h = 0.5f * ang;
      cs[t] = make_float2(cosf(h), sinf(h));
    }
  }
  __syncthreads();

  int k = blockIdx.x;  // basis column
  float a0 = ((k >> 6) == 0 && (k & 63) == lane) ? 1.0f : 0.0f;
  float a1 = ((k >> 6) == 1 && (k & 63) == lane) ? 1.0f : 0.0f;
  int gi = 0;

  const int qcstep[6] = {4, 1, 2, 1, 1, 1};
#define RYG(w)                                        \
  { float2 csv = cs[gi++]; ry_gate(a0, a1, (w), lane, csv.x, csv.y); }
#define CNG(c, t) cnot_gate(a0, a1, (c), (t), lane);

#pragma unroll
  for (int j = 0; j < 6; ++j) {
    int sq = 7 - j;
    int step = qcstep[j];
    for (int i = 0; i < sq; ++i) { RYG(i); }
    for (int i = 0; i < sq; ++i) {
      if (i == 0) { RYG(0); CNG(sq - 1, 0); RYG(0); }
      else { int w = sq - i; RYG(w); CNG(w - 1, w); RYG(w); }
    }
    for (int i = 0; i < sq; ++i) { RYG(i); }
    int control = 0, controled = step;
    for (int i = 0; i < sq; ++i) {
      RYG(controled); CNG(control, controled); RYG(controled);
      control = controled; controled = (controled + step) % sq;
    }
    for (int i = 0; i < sq - 1; ++i) { RYG(i + 1); CNG(i, i + 1); RYG(i + 1); }
  }
  RYG(0);  // final QF rotation (index 204)
#undef RYG
#undef CNG

  // scatter to 32x32 B-fragment order
  {
    int ks = k >> 4, hi2 = (k >> 3) & 1, j = k & 7;
    int nfa = lane >> 5, c5 = lane & 31;
    wt[(ks * 4 + nfa) * 512 + hi2 * 256 + c5 * 8 + j] = (_Float16)a0;      // n=lane
    wt[(ks * 4 + 2 + nfa) * 512 + hi2 * 256 + c5 * 8 + j] = (_Float16)a1;  // n=lane+64
  }
}

// ---------------- kernel 2: Z = X * U^T via 32x32x16 MFMA -------------------
// mfma_f32_32x32x16_f16: A lane l holds A[l&31][(l>>5)*8 + j]  (8 f16, 4 VGPR)
//                        B lane l holds B[(l>>5)*8 + j][l&31]
//                        D lane l holds D[(reg&3)+8*(reg>>2)+4*(l>>5)][l&31], reg 0..15
// Per wave-tile (32 rows): 32 ds_read_b128 (half of the 16x16 design) +
// reduce-scatter epilogue (32 shfl, half of butterfly) -> DS work halved.
// A-loads software-pipelined 2 ks-steps deep (~16 float regs in flight).
__global__ __launch_bounds__(256, 4) void qcnn_gemm(
    const float* __restrict__ X, const _Float16* __restrict__ wt,
    float* __restrict__ out, int M) {
  __shared__ uint4 ldsbuf[2048];  // 32 KB: W in 32x32 fragment order
  int tid = threadIdx.x;
  int wave = tid >> 6, lane = tid & 63;
  int r5 = lane & 31;  // A row / B,D col within tile
  int hi = lane >> 5;  // k-octet group (A,B) / row-half (D)

  // stage W -> LDS: straight linear copy, fully coalesced
  {
    const uint4* wv = (const uint4*)wt;
#pragma unroll
    for (int c = 0; c < 8; ++c) ldsbuf[c * 256 + tid] = wv[c * 256 + tid];
  }
  __syncthreads();

  const char* bbase = (const char*)ldsbuf + lane * 16;

#pragma unroll
  for (int t = 0; t < 2; ++t) {
    int rb = blockIdx.x * 256 + wave * 32 + t * 128;  // exact fit: no bounds check
    const float* xp = X + (size_t)(rb + r5) * 128 + hi * 8;

    float4 f0[8], f1[8];
    // prologue: ks=0,1 loads in flight
    f0[0] = *(const float4*)(xp);          f1[0] = *(const float4*)(xp + 4);
    f0[1] = *(const float4*)(xp + 16);     f1[1] = *(const float4*)(xp + 20);

    f32x16 acc[4];
#pragma unroll
    for (int nf = 0; nf < 4; ++nf)
#pragma unroll
      for (int e = 0; e < 16; ++e) acc[nf][e] = 0.f;

#pragma unroll
    for (int ks = 0; ks < 8; ++ks) {
      if (ks + 2 < 8) {  // issue 2-ahead loads
        f0[ks + 2] = *(const float4*)(xp + (ks + 2) * 16);
        f1[ks + 2] = *(const float4*)(xp + (ks + 2) * 16 + 4);
      }
      auto p0 = __builtin_amdgcn_cvt_pkrtz(f0[ks].x, f0[ks].y);
      auto p1 = __builtin_amdgcn_cvt_pkrtz(f0[ks].z, f0[ks].w);
      auto p2 = __builtin_amdgcn_cvt_pkrtz(f1[ks].x, f1[ks].y);
      auto p3 = __builtin_amdgcn_cvt_pkrtz(f1[ks].z, f1[ks].w);
      f16x8 a;
      a[0] = (_Float16)p0[0]; a[1] = (_Float16)p0[1];
      a[2] = (_Float16)p1[0]; a[3] = (_Float16)p1[1];
      a[4] = (_Float16)p2[0]; a[5] = (_Float16)p2[1];
      a[6] = (_Float16)p3[0]; a[7] = (_Float16)p3[1];
#pragma unroll
      for (int nf = 0; nf < 4; ++nf) {
        f16x8 b = *(const f16x8*)(bbase + ((ks * 4 + nf) << 10));
        acc[nf] = __builtin_amdgcn_mfma_f32_32x32x16_f16(a, b, acc[nf], 0, 0, 0);
      }
    }

    // ---- epilogue: per-reg partials v[j], j = reg*2 + h (h: 0=cols<64) ----
    float v[32];
#pragma unroll
    for (int rg = 0; rg < 16; ++rg) {
      v[rg * 2 + 0] = acc[0][rg] * acc[0][rg] + acc[1][rg] * acc[1][rg];
      v[rg * 2 + 1] = acc[2][rg] * acc[2][rg] + acc[3][rg] * acc[3][rg];
    }
    // reduce-scatter over 32 cols: rounds d=1,2,4,8,16 consume j bits 0..4.
    // final: lane owns j = lane&31 -> reg = (lane>>1)&15, h = lane&1.
    int kb = lane & 1;
    float n1[16];
#pragma unroll
    for (int i = 0; i < 16; ++i) {
      float snd = kb ? v[2 * i] : v[2 * i + 1];
      float rcv = __shfl_xor(snd, 1);
      n1[i] = (kb ? v[2 * i + 1] : v[2 * i]) + rcv;
    }
    int kb2 = (lane >> 1) & 1;
    float n2[8];
#pragma unroll
    for (int i = 0; i < 8; ++i) {
      float snd = kb2 ? n1[2 * i] : n1[2 * i + 1];
      float rcv = __shfl_xor(snd, 2);
      n2[i] = (kb2 ? n1[2 * i + 1] : n1[2 * i]) + rcv;
    }
    int kb3 = (lane >> 2) & 1;
    float n3[4];
#pragma unroll
    for (int i = 0; i < 4; ++i) {
      float snd = kb3 ? n2[2 * i] : n2[2 * i + 1];
      float rcv = __shfl_xor(snd, 4);
      n3[i] = (kb3 ? n2[2 * i + 1] : n2[2 * i]) + rcv;
    }
    int kb4 = (lane >> 3) & 1;
    float n4[2];
#pragma unroll
    for (int i = 0; i < 2; ++i) {
      float snd = kb4 ? n3[2 * i] : n3[2 * i + 1];
      float rcv = __shfl_xor(snd, 8);
      n4[i] = (kb4 ? n3[2 * i + 1] : n3[2 * i]) + rcv;
    }
    int kb5 = (lane >> 4) & 1;
    {
      float snd = kb5 ? n4[0] : n4[1];
      float rcv = __shfl_xor(snd, 16);
      float S = (kb5 ? n4[1] : n4[0]) + rcv;
      float T = __shfl_xor(S, 1);  // partner holds the other half's sum
      float prob = S / (S + T);
      int reg = (lane >> 1) & 15;
      int row = (reg & 3) + 8 * (reg >> 2) + 4 * hi;
      out[(size_t)(rb + row) * 2 + (lane & 1)] = prob;
    }
  }
}

// ---------------------------------------------------------------------------
extern "C" void kernel_launch(void* const* d_in, const int* in_sizes, int n_in,
                              void* d_out, int out_size, void* d_ws,
                              size_t ws_size, hipStream_t stream) {
  const float* X = (const float*)d_in[0];
  _Float16* wt = (_Float16*)d_ws;  // 128*128 f16 = 32 KB, 32x32 fragment order

  // setup_inputs() dict order is INTERLEAVED: x, QC1, QP1, QC2, QP2, ...,
  // QC6, QP6, QF.
  basis_kernel<<<128, 64, 0, stream>>>(
      /*qc1*/ (const float*)d_in[1], /*qc2*/ (const float*)d_in[3],
      /*qc3*/ (const float*)d_in[5], /*qc4*/ (const float*)d_in[7],
      /*qc5*/ (const float*)d_in[9], /*qc6*/ (const float*)d_in[11],
      /*qp1*/ (const float*)d_in[2], /*qp2*/ (const float*)d_in[4],
      /*qp3*/ (const float*)d_in[6], /*qp4*/ (const float*)d_in[8],
      /*qp5*/ (const float*)d_in[10], /*qp6*/ (const float*)d_in[12],
      /*qf*/ (const float*)d_in[13], wt);

  int M = in_sizes[0] / 128;   // 262144
  int nblk = (M + 255) / 256;  // 1024 blocks of 256 rows
  qcnn_gemm<<<nblk, 256, 0, stream>>>(X, wt, (float*)d_out, M);
}

// Round 14
// 39.134 us; speedup vs baseline: 3.0843x; 1.1362x over previous
//
#include <hip/hip_runtime.h>

typedef _Float16 f16x8 __attribute__((ext_vector_type(8)));
typedef float f32x4 __attribute__((ext_vector_type(4)));

// ---------------- gate primitives (state: 128 amps, 2 per lane) -------------
// amp index i = (r<<6) | lane, wire w <-> bit (6-w) (wire 0 = MSB = register)

__device__ __forceinline__ void ry_gate(float& a0, float& a1, int w, int lane,
                                        float c, float s) {
  if (w == 0) {
    float n0 = c * a0 - s * a1;
    float n1 = s * a0 + c * a1;
    a0 = n0; a1 = n1;
  } else {
    int m = 1 << (6 - w);
    float p0 = __shfl_xor(a0, m);
    float p1 = __shfl_xor(a1, m);
    if (lane & m) {
      a0 = s * p0 + c * a0;
      a1 = s * p1 + c * a1;
    } else {
      a0 = c * a0 - s * p0;
      a1 = c * a1 - s * p1;
    }
  }
}

// merged {RY(th1,t); CNOT(cw,t); RY(th2,t)}: acts on pair (n, n^mt) as a 2x2
// selected by the c-bit:  c=0: RY(th1+th2);  c=1: (x,y)->(-sm*x+cm*y, cm*x+sm*y)
// with cp=cos(h1+h2), sp=sin(h1+h2), cm=cos(h2-h1), sm=sin(h2-h1) (h=theta/2).
// ONE shfl pair instead of three chain steps.
__device__ __forceinline__ void pair_op(float& a0, float& a1, int cw, int tw,
                                        int lane, float c1, float s1,
                                        float c2, float s2) {
  float cp = c1 * c2 - s1 * s2;
  float sp = s1 * c2 + c1 * s2;
  float cm = c1 * c2 + s1 * s2;
  float sm = s2 * c1 - c2 * s1;
  if (tw == 0) {            // target wire 0: register-local pair, no shfl
    int mc = 1 << (6 - cw);
    bool cb = (lane & mc) != 0;
    float n0 = cb ? (cm * a1 - sm * a0) : (cp * a0 - sp * a1);
    float n1 = cb ? (cm * a0 + sm * a1) : (sp * a0 + cp * a1);
    a0 = n0; a1 = n1;
  } else if (cw == 0) {     // control wire 0: c-bit IS the register index
    int mt = 1 << (6 - tw);
    float p0 = __shfl_xor(a0, mt);
    float p1 = __shfl_xor(a1, mt);
    bool tb = (lane & mt) != 0;
    a0 = tb ? (sp * p0 + cp * a0) : (cp * a0 - sp * p0);
    a1 = tb ? (sm * a1 + cm * p1) : (cm * p1 - sm * a1);
  } else {                  // both lane bits
    int mt = 1 << (6 - tw), mc = 1 << (6 - cw);
    float p0 = __shfl_xor(a0, mt);
    float p1 = __shfl_xor(a1, mt);
    bool tb = (lane & mt) != 0, cb = (lane & mc) != 0;
    float own = cb ? (tb ? sm : -sm) : cp;
    float par = cb ? cm : (tb ? sp : -sp);
    a0 = own * a0 + par * p0;
    a1 = own * a1 + par * p1;
  }
}

// ------- kernel 1: build U, store in MFMA B-FRAGMENT order (f16) -----------
// frag layout: element (n,k):
//   f16 idx = ((k>>5)*8 + (n>>4))*512 + ((k>>3)&3)*128 + (n&15)*8 + (k&7)
__global__ __launch_bounds__(64) void basis_kernel(
    const float* __restrict__ qc1, const float* __restrict__ qc2,
    const float* __restrict__ qc3, const float* __restrict__ qc4,
    const float* __restrict__ qc5, const float* __restrict__ qc6,
    const float* __restrict__ qp1, const float* __restrict__ qp2,
    const float* __restrict__ qp3, const float* __restrict__ qp4,
    const float* __restrict__ qp5, const float* __restrict__ qp6,
    const float* __restrict__ qf, _Float16* __restrict__ wt) {
  __shared__ float2 cs[208];
  int lane = threadIdx.x;

  // angles laid out flat: [QC1,QP1,QC2,QP2,...,QC6,QP6,QF] -> (cos,sin)(a/2)
  {
    const float* arrs[13] = {qc1, qp1, qc2, qp2, qc3, qp3, qc4,
                             qp4, qc5, qp5, qc6, qp6, qf};
    const int sizes[13] = {42, 12, 36, 10, 30, 8, 24, 6, 18, 4, 12, 2, 1};
    for (int t = lane; t < 205; t += 64) {
      int base = 0; float ang = 0.f;
#pragma unroll
      for (int s2 = 0; s2 < 13; ++s2) {
        if (t >= base && t < base + sizes[s2]) ang = arrs[s2][t - base];
        base += sizes[s2];
      }
      float h = 0.5f * ang;
      cs[t] = make_float2(cosf(h), sinf(h));
    }
  }
  __syncthreads();

  int k = blockIdx.x;  // basis column
  float a0 = ((k >> 6) == 0 && (k & 63) == lane) ? 1.0f : 0.0f;
  float a1 = ((k >> 6) == 1 && (k & 63) == lane) ? 1.0f : 0.0f;
  int gi = 0;

  const int qcstep[6] = {4, 1, 2, 1, 1, 1};
#define RYG(w)                                        \
  { float2 v = cs[gi++]; ry_gate(a0, a1, (w), lane, v.x, v.y); }
#define PAIR(c, t)                                    \
  { float2 v1 = cs[gi], v2 = cs[gi + 1]; gi += 2;     \
    pair_op(a0, a1, (c), (t), lane, v1.x, v1.y, v2.x, v2.y); }

#pragma unroll
  for (int j = 0; j < 6; ++j) {
    int sq = 7 - j;
    int step = qcstep[j];
    for (int i = 0; i < sq; ++i) { RYG(i); }            // sweep 1
    for (int i = 0; i < sq; ++i) {                      // ring entangle (merged)
      if (i == 0) { PAIR(sq - 1, 0); }
      else { int w = sq - i; PAIR(w - 1, w); }
    }
    for (int i = 0; i < sq; ++i) { RYG(i); }            // sweep 2
    int control = 0, controled = step;                  // skip entangle (merged)
    for (int i = 0; i < sq; ++i) {
      PAIR(control, controled);
      control = controled; controled = (controled + step) % sq;
    }
    for (int i = 0; i < sq - 1; ++i) { PAIR(i, i + 1); }  // qp chain (merged)
  }
  RYG(0);  // final QF rotation (index 204)
#undef RYG
#undef PAIR

  // scatter to fragment order
  {
    int ks = k >> 5, khi = (k >> 3) & 3, j = k & 7;
    int nf0 = lane >> 4, lr0 = lane & 15;
    wt[(ks * 8 + nf0) * 512 + khi * 128 + lr0 * 8 + j] = (_Float16)a0;
    wt[(ks * 8 + nf0 + 4) * 512 + khi * 128 + lr0 * 8 + j] = (_Float16)a1;
  }
}

// ---------------- kernel 2: Z = X * U^T, out = row-half prob ----------------
// (byte-identical to round 6 — best measured: warm ~20 us = L3-fabric stream
//  ceiling ~6.6 TB/s; VGPR 64, fragment-order W in LDS, conflict-free reads)
__global__ __launch_bounds__(256, 4) void qcnn_gemm(
    const float* __restrict__ X, const _Float16* __restrict__ wt,
    float* __restrict__ out, int M) {
  __shared__ uint4 ldsbuf[2048];  // 32 KB: W in fragment order
  int tid = threadIdx.x;
  int wave = tid >> 6, lane = tid & 63;
  int lr = lane & 15;
  int g = lane >> 4;
  int lk = g * 8;

  size_t base0 = (size_t)blockIdx.x * 256 + wave * 16;  // this wave's row base

  // prefetch iter-0 X loads (in flight during LDS staging + barrier)
  float4 v0[4], v1[4];
  if (base0 < (size_t)M) {
    const float* xp = X + (base0 + lr) * 128 + lk;
#pragma unroll
    for (int ks = 0; ks < 4; ++ks) {
      v0[ks] = *(const float4*)(xp + ks * 32);
      v1[ks] = *(const float4*)(xp + ks * 32 + 4);
    }
  }

  // stage W -> LDS: straight linear copy, fully coalesced
  {
    const uint4* wv = (const uint4*)wt;
#pragma unroll
    for (int c = 0; c < 8; ++c) ldsbuf[c * 256 + tid] = wv[c * 256 + tid];
  }
  __syncthreads();

  const char* bbase = (const char*)ldsbuf + lane * 16;

#pragma unroll
  for (int t = 0; t < 4; ++t) {
    size_t rb = base0 + (size_t)t * 64;
    if (rb < (size_t)M) {
      // convert current tile to f16 A-fragments (frees v0/v1)
      f16x8 a[4];
#pragma unroll
      for (int ks = 0; ks < 4; ++ks) {
        auto p0 = __builtin_amdgcn_cvt_pkrtz(v0[ks].x, v0[ks].y);
        auto p1 = __builtin_amdgcn_cvt_pkrtz(v0[ks].z, v0[ks].w);
        auto p2 = __builtin_amdgcn_cvt_pkrtz(v1[ks].x, v1[ks].y);
        auto p3 = __builtin_amdgcn_cvt_pkrtz(v1[ks].z, v1[ks].w);
        f16x8 f;
        f[0] = (_Float16)p0[0]; f[1] = (_Float16)p0[1];
        f[2] = (_Float16)p1[0]; f[3] = (_Float16)p1[1];
        f[4] = (_Float16)p2[0]; f[5] = (_Float16)p2[1];
        f[6] = (_Float16)p3[0]; f[7] = (_Float16)p3[1];
        a[ks] = f;
      }

      // issue next tile's loads early — in flight during MFMA + epilogue
      if (t < 3) {
        size_t rn = base0 + (size_t)(t + 1) * 64;
        if (rn < (size_t)M) {
          const float* xp = X + (rn + lr) * 128 + lk;
#pragma unroll
          for (int ks = 0; ks < 4; ++ks) {
            v0[ks] = *(const float4*)(xp + ks * 32);
            v1[ks] = *(const float4*)(xp + ks * 32 + 4);
          }
        }
      }

      f32x4 acc[8];
#pragma unroll
      for (int nf = 0; nf < 8; ++nf) acc[nf] = (f32x4){0.f, 0.f, 0.f, 0.f};

#pragma unroll
      for (int ks = 0; ks < 4; ++ks) {
#pragma unroll
        for (int nf = 0; nf < 8; ++nf) {
          f16x8 b = *(const f16x8*)(bbase + (ks * 8 + nf) * 1024);
          acc[nf] = __builtin_amdgcn_mfma_f32_16x16x32_f16(a[ks], b, acc[nf], 0, 0, 0);
        }
      }

      // epilogue: s0 = sum_{n<64} z^2, s1 = sum_{n>=64} z^2 per row
      float s0[4], s1[4];
#pragma unroll
      for (int r = 0; r < 4; ++r) {
        float t0 = 0.f, t1 = 0.f;
#pragma unroll
        for (int nf = 0; nf < 4; ++nf) t0 += acc[nf][r] * acc[nf][r];
#pragma unroll
        for (int nf = 4; nf < 8; ++nf) t1 += acc[nf][r] * acc[nf][r];
        s0[r] = t0; s1[r] = t1;
      }
#pragma unroll
      for (int d = 1; d < 16; d <<= 1) {  // reduce across the 16-lane group
#pragma unroll
        for (int r = 0; r < 4; ++r) {
          s0[r] += __shfl_xor(s0[r], d);
          s1[r] += __shfl_xor(s1[r], d);
        }
      }
      size_t row = rb + g * 4;
#pragma unroll
      for (int r = 0; r < 4; ++r) {
        if ((lane & 15) == r) {
          float inv = 1.0f / (s0[r] + s1[r]);
          *(float2*)(out + (row + r) * 2) =
              make_float2(s0[r] * inv, s1[r] * inv);
        }
      }
    }
  }
}

// ---------------------------------------------------------------------------
extern "C" void kernel_launch(void* const* d_in, const int* in_sizes, int n_in,
                              void* d_out, int out_size, void* d_ws,
                              size_t ws_size, hipStream_t stream) {
  const float* X = (const float*)d_in[0];
  _Float16* wt = (_Float16*)d_ws;  // 128*128 f16 = 32 KB, fragment order

  // setup_inputs() dict order is INTERLEAVED: x, QC1, QP1, QC2, QP2, ...,
  // QC6, QP6, QF.
  basis_kernel<<<128, 64, 0, stream>>>(
      /*qc1*/ (const float*)d_in[1], /*qc2*/ (const float*)d_in[3],
      /*qc3*/ (const float*)d_in[5], /*qc4*/ (const float*)d_in[7],
      /*qc5*/ (const float*)d_in[9], /*qc6*/ (const float*)d_in[11],
      /*qp1*/ (const float*)d_in[2], /*qp2*/ (const float*)d_in[4],
      /*qp3*/ (const float*)d_in[6], /*qp4*/ (const float*)d_in[8],
      /*qp5*/ (const float*)d_in[10], /*qp6*/ (const float*)d_in[12],
      /*qf*/ (const float*)d_in[13], wt);

  int M = in_sizes[0] / 128;   // 262144
  int nblk = (M + 255) / 256;  // 1024 blocks of 256 rows
  qcnn_gemm<<<nblk, 256, 0, stream>>>(X, wt, (float*)d_out, M);
}